// Round 1
// baseline (14577.460 us; speedup 1.0000x reference)
//
#include <hip/hip_runtime.h>

typedef unsigned short u16;
typedef unsigned int u32;
typedef __bf16 bf16x8 __attribute__((ext_vector_type(8)));
typedef float f32x4 __attribute__((ext_vector_type(4)));

__device__ __forceinline__ u16 f2bf(float f) {
  u32 u = __builtin_bit_cast(u32, f);
  u = (u + 0x7FFFu + ((u >> 16) & 1u)) >> 16;
  return (u16)u;
}

static inline int cdiv(int a, int b) { return (a + b - 1) / b; }

// ---------------------------------------------------------------------------
// K1: fp32 gathered sparse-conv / GEMM.  out[m,co] = sum_k sum_ci
//     A[nmap[m,k], aoff+ci] * W[k,ci,co].  nmap==null -> identity (dense GEMM).
// Tile: 64x64, BK=16, 256 threads, 4x4 register tile per thread.
// ---------------------------------------------------------------------------
__global__ __launch_bounds__(256) void k1_conv(
    const float* __restrict__ A, int lda, int aoff, int Cin,
    const int* __restrict__ nmap, int K,
    const float* __restrict__ W, int Cout,
    const float* __restrict__ bias,
    float* __restrict__ out, int ldo, int M) {
  __shared__ float As[16][64];
  __shared__ float Ws[16][64];
  __shared__ int idxs[64];
  const int tid = threadIdx.x;
  const int m0 = blockIdx.x * 64;
  const int n0 = blockIdx.y * 64;
  const int tr = (tid >> 4) << 2;
  const int tc = (tid & 15) << 2;
  float acc[4][4] = {{0.f}};
  for (int k = 0; k < K; ++k) {
    __syncthreads();
    if (tid < 64) {
      int m = m0 + tid;
      int idx = -1;
      if (m < M) idx = nmap ? nmap[(long)m * K + k] : m;
      idxs[tid] = idx;
    }
    __syncthreads();
    for (int c0 = 0; c0 < Cin; c0 += 16) {
      {
        int r = tid & 63;
        int cb = (tid >> 6) << 2;
        int idx = idxs[r];
        const float* src = A + (long)idx * lda + aoff + c0;
#pragma unroll
        for (int i = 0; i < 4; ++i) {
          int ci = c0 + cb + i;
          As[cb + i][r] = (idx >= 0 && ci < Cin) ? src[cb + i] : 0.f;
        }
      }
      {
        int co = tid & 63;
        int cb = (tid >> 6) << 2;
        const float* wsrc = W + ((long)k * Cin + c0) * Cout + n0 + co;
#pragma unroll
        for (int i = 0; i < 4; ++i) {
          int ci = c0 + cb + i;
          Ws[cb + i][co] = (ci < Cin) ? wsrc[(long)(cb + i) * Cout] : 0.f;
        }
      }
      __syncthreads();
#pragma unroll
      for (int kk = 0; kk < 16; ++kk) {
        float a[4], b[4];
#pragma unroll
        for (int i = 0; i < 4; ++i) a[i] = As[kk][tr + i];
#pragma unroll
        for (int j = 0; j < 4; ++j) b[j] = Ws[kk][tc + j];
#pragma unroll
        for (int i = 0; i < 4; ++i)
#pragma unroll
          for (int j = 0; j < 4; ++j) acc[i][j] += a[i] * b[j];
      }
      __syncthreads();
    }
  }
#pragma unroll
  for (int i = 0; i < 4; ++i) {
    int m = m0 + tr + i;
    if (m >= M) continue;
#pragma unroll
    for (int j = 0; j < 4; ++j) {
      int co = n0 + tc + j;
      float v = acc[i][j];
      if (bias) v += bias[co];
      out[(long)m * ldo + co] = v;
    }
  }
}

// ---------------------------------------------------------------------------
// K2: bf16 MFMA gathered sparse-conv.  A is bf16 [*, lda]; WT is bf16
// pre-transposed [k][WTR][CP] (WTR = cdiv(Cout,16)*16 rows, zero-padded;
// CP = cdiv(Cin,64)*64, zero-padded).  Block tile 128 x 192; 4 waves, each
// wave = 4 row-strips x 6 col-tiles of mfma_f32_16x16x32_bf16.
// ---------------------------------------------------------------------------
#define K2_SA 72
__global__ __launch_bounds__(256) void k2_conv(
    const u16* __restrict__ A, int lda,
    const int* __restrict__ nmap, int K,
    const u16* __restrict__ WT, int WTR, int CP,
    int Cout,
    const float* __restrict__ bias,
    float* __restrict__ of, int ldo,
    u16* __restrict__ ob, int ldb,
    int M) {
  __shared__ __align__(16) u16 As[128 * K2_SA];
  __shared__ __align__(16) u16 Ws[192 * K2_SA];
  __shared__ int idxs[128];
  const int tid = threadIdx.x;
  const int m0 = blockIdx.x * 128;
  const int lane = tid & 63;
  const int w = tid >> 6;
  const int wr = w >> 1, wc = w & 1;
  const int ln = lane & 15, qd = lane >> 4;
  int NTT = (Cout + 15) >> 4;
  int NTw = NTT - wc * 6;
  if (NTw < 0) NTw = 0;
  if (NTw > 6) NTw = 6;
  const int NSB = CP >> 6;
  f32x4 acc[4][6];
  f32x4 zero = {0.f, 0.f, 0.f, 0.f};
#pragma unroll
  for (int i = 0; i < 4; ++i)
#pragma unroll
    for (int j = 0; j < 6; ++j) acc[i][j] = zero;

  for (int k = 0; k < K; ++k) {
    __syncthreads();
    if (tid < 128) {
      int m = m0 + tid;
      idxs[tid] = (m < M) ? (nmap ? nmap[(long)m * K + k] : m) : -1;
    }
    __syncthreads();
    for (int sb = 0; sb < NSB; ++sb) {
      {  // stage A (gather): 128 rows x 64 ci, 2 threads/row
        int r = tid >> 1;
        int s0 = (tid & 1) << 2;
        int idx = idxs[r];
        const u16* src = A + (long)idx * lda + sb * 64;
#pragma unroll
        for (int i = 0; i < 4; ++i) {
          int s = s0 + i;
          int ci = sb * 64 + s * 8;
          uint4 v = make_uint4(0u, 0u, 0u, 0u);
          if (idx >= 0 && ci + 8 <= lda) v = *(const uint4*)(src + s * 8);
          *(uint4*)&As[r * K2_SA + s * 8] = v;
        }
      }
      {  // stage W (contiguous, pre-transposed): 192 rows x 64 ci
        const u16* wk = WT + (long)k * WTR * CP + sb * 64;
        for (int i = tid; i < 192 * 8; i += 256) {
          int co = i >> 3, s = i & 7;
          uint4 v = make_uint4(0u, 0u, 0u, 0u);
          if (co < WTR) v = *(const uint4*)(wk + (long)co * CP + s * 8);
          *(uint4*)&Ws[co * K2_SA + s * 8] = v;
        }
      }
      __syncthreads();
      if (NTw > 0) {
#pragma unroll
        for (int ch = 0; ch < 2; ++ch) {
          int koff = ch * 32 + qd * 8;
          bf16x8 a[4];
#pragma unroll
          for (int st = 0; st < 4; ++st)
            a[st] = *(const bf16x8*)&As[(wr * 64 + st * 16 + ln) * K2_SA + koff];
#pragma unroll
          for (int nt = 0; nt < 6; ++nt) {
            if (nt < NTw) {
              bf16x8 b = *(const bf16x8*)&Ws[(wc * 96 + nt * 16 + ln) * K2_SA + koff];
#pragma unroll
              for (int st = 0; st < 4; ++st)
                acc[st][nt] = __builtin_amdgcn_mfma_f32_16x16x32_bf16(a[st], b, acc[st][nt], 0, 0, 0);
            }
          }
        }
      }
      __syncthreads();
    }
  }
#pragma unroll
  for (int nt = 0; nt < 6; ++nt) {
    if (nt >= NTw) continue;
    int col = wc * 96 + nt * 16 + ln;
    if (col >= Cout) continue;
    float bv = bias ? bias[col] : 0.f;
#pragma unroll
    for (int st = 0; st < 4; ++st) {
#pragma unroll
      for (int i = 0; i < 4; ++i) {
        int m = m0 + wr * 64 + st * 16 + qd * 4 + i;
        if (m < M) {
          float v = acc[st][nt][i] + bv;
          if (of) of[(long)m * ldo + col] = v;
          if (ob) ob[(long)m * ldb + col] = f2bf(v);
        }
      }
    }
  }
}

// ---------------------------------------------------------------------------
// stats: per-(batch,channel) sum / sumsq (+count) for instance norm.
// slot layout: [sum0(C), sq0(C), sum1(C), sq1(C), cnt0, cnt1]
// ---------------------------------------------------------------------------
__global__ __launch_bounds__(256) void k_stats(
    const float* __restrict__ x, int ld, int M, int C,
    const int* __restrict__ bidx, float* __restrict__ st) {
  int c = threadIdx.x;
  int rpb = (M + gridDim.x - 1) / gridDim.x;
  int r0 = blockIdx.x * rpb;
  int r1 = r0 + rpb;
  if (r1 > M) r1 = M;
  float s0 = 0.f, q0 = 0.f, s1 = 0.f, q1 = 0.f, n0 = 0.f, n1 = 0.f;
  for (int r = r0; r < r1; ++r) {
    int b = bidx[r];
    if (c < C) {
      float v = x[(long)r * ld + c];
      if (b == 0) { s0 += v; q0 += v * v; } else { s1 += v; q1 += v * v; }
    }
    if (c == 0) { if (b == 0) n0 += 1.f; else n1 += 1.f; }
  }
  if (c < C) {
    if (s0 != 0.f || q0 != 0.f) { atomicAdd(&st[c], s0); atomicAdd(&st[C + c], q0); }
    if (s1 != 0.f || q1 != 0.f) { atomicAdd(&st[2 * C + c], s1); atomicAdd(&st[3 * C + c], q1); }
  }
  if (c == 0) {
    if (n0 != 0.f) atomicAdd(&st[4 * C], n0);
    if (n1 != 0.f) atomicAdd(&st[4 * C + 1], n1);
  }
}

// ---------------------------------------------------------------------------
// apply: v = (x - mean)*rsqrt(var+eps) [+ res] [relu] -> optional f32 / bf16
// ---------------------------------------------------------------------------
__global__ __launch_bounds__(256) void k_apply(
    const float* __restrict__ x, int ldx, int M, int C,
    const int* __restrict__ bidx, const float* __restrict__ st,
    const float* __restrict__ res, int ldr, int relu,
    float* __restrict__ of, int ldo, u16* __restrict__ ob, int ldb) {
  __shared__ float mean_s[2][192];
  __shared__ float inv_s[2][192];
  for (int j = threadIdx.x; j < 2 * C; j += 256) {
    int b = (j >= C) ? 1 : 0;
    int c = j - b * C;
    float cnt = st[4 * C + b];
    float mean = st[b * 2 * C + c] / cnt;
    float var = st[b * 2 * C + C + c] / cnt - mean * mean;
    mean_s[b][c] = mean;
    inv_s[b][c] = 1.f / sqrtf(fmaxf(var, 0.f) + 1e-5f);
  }
  __syncthreads();
  long total = (long)M * C;
  long stride = (long)gridDim.x * 256;
  for (long i = (long)blockIdx.x * 256 + threadIdx.x; i < total; i += stride) {
    int r = (int)(i / C);
    int c = (int)(i - (long)r * C);
    int b = bidx[r];
    float v = (x[(long)r * ldx + c] - mean_s[b][c]) * inv_s[b][c];
    if (res) v += res[(long)r * ldr + c];
    if (relu) v = fmaxf(v, 0.f);
    if (of) of[(long)r * ldo + c] = v;
    if (ob) ob[(long)r * ldb + c] = f2bf(v);
  }
}

// proxy = sparse @ W_occ + b_occ ; mask = proxy > 0 ; sp = mask ? sparse : 0
__global__ __launch_bounds__(256) void k_mask(
    const float* __restrict__ sp, const float* __restrict__ Wocc,
    const float* __restrict__ bocc, float* __restrict__ proxy,
    float* __restrict__ catf, u16* __restrict__ catb, int M) {
  int r = blockIdx.x * 4 + (threadIdx.x >> 6);
  int lane = threadIdx.x & 63;
  if (r >= M) return;
  float v0 = sp[(long)r * 128 + lane];
  float v1 = sp[(long)r * 128 + 64 + lane];
  float s = v0 * Wocc[lane] + v1 * Wocc[64 + lane];
  for (int off = 32; off > 0; off >>= 1) s += __shfl_down(s, off);
  s = __shfl(s, 0);
  float p = s + bocc[0];
  if (lane == 0) proxy[r] = p;
  bool m = p > 0.0f;
  float w0 = m ? v0 : 0.f, w1 = m ? v1 : 0.f;
  catf[(long)r * 192 + 64 + lane] = w0;
  catf[(long)r * 192 + 128 + lane] = w1;
  catb[(long)r * 192 + 64 + lane] = f2bf(w0);
  catb[(long)r * 192 + 128 + lane] = f2bf(w1);
}

// copy cat -> full[:,0:192] and zero full[:,229:232]
__global__ __launch_bounds__(256) void k_full(
    const u16* __restrict__ catb, u16* __restrict__ full, int M) {
  long total = (long)M * 195;
  long stride = (long)gridDim.x * 256;
  for (long i = (long)blockIdx.x * 256 + threadIdx.x; i < total; i += stride) {
    int r = (int)(i / 195);
    int j = (int)(i - (long)r * 195);
    if (j < 192)
      full[(long)r * 232 + j] = catb[(long)r * 192 + j];
    else
      full[(long)r * 232 + 229 + (j - 192)] = 0;
  }
}

// weight convert: src f32 [K][Cin][Cout] -> dst bf16 transposed [K][WTR][CP]
__global__ __launch_bounds__(256) void k_wconv(
    const float* __restrict__ src, u16* __restrict__ dst,
    int K, int Cin, int Cout, int WTR, int CP) {
  long total = (long)K * WTR * CP;
  long stride = (long)gridDim.x * 256;
  for (long i = (long)blockIdx.x * 256 + threadIdx.x; i < total; i += stride) {
    int ci = (int)(i % CP);
    long t = i / CP;
    int co = (int)(t % WTR);
    int k = (int)(t / WTR);
    float v = 0.f;
    if (ci < Cin && co < Cout) v = src[((long)k * Cin + ci) * Cout + co];
    dst[i] = f2bf(v);
  }
}

// ---------------------------------------------------------------------------
extern "C" void kernel_launch(void* const* d_in, const int* in_sizes, int n_in,
                              void* d_out, int out_size, void* d_ws, size_t ws_size,
                              hipStream_t stream) {
  const float* features = (const float*)d_in[0];
  const int* nmap1 = (const int*)d_in[1];
  const int* cmap = (const int*)d_in[2];
  const int* nmap2 = (const int*)d_in[3];
  const int* b1 = (const int*)d_in[4];
  const int* b2 = (const int*)d_in[5];
  const int* b3 = (const int*)d_in[6];
  const float* W_d1 = (const float*)d_in[7];
  const float* W_d2 = (const float*)d_in[8];
  const float* Wd_d = (const float*)d_in[9];
  const float* W_f1 = (const float*)d_in[11];
  const float* W_f2 = (const float*)d_in[12];
  const float* Wd_f = (const float*)d_in[13];
  const float* W_i1 = (const float*)d_in[15];
  const float* W_i2 = (const float*)d_in[16];
  const float* Wd_i = (const float*)d_in[17];
  const float* W_e1a = (const float*)d_in[19];
  const float* W_e1b = (const float*)d_in[20];
  const float* W_ed = (const float*)d_in[21];
  const float* W_e2a = (const float*)d_in[23];
  const float* W_e2b = (const float*)d_in[24];
  const float* W_sub = (const float*)d_in[25];
  const float* b_sub = (const float*)d_in[26];
  const float* W_occ = (const float*)d_in[27];
  const float* b_occ = (const float*)d_in[28];
  const float* W_pi1 = (const float*)d_in[29];
  const float* W_pi2 = (const float*)d_in[30];
  const float* W_pi3 = (const float*)d_in[31];
  const float* b_pi3 = (const float*)d_in[32];
  const float* W_ps1 = (const float*)d_in[33];
  const float* W_ps2 = (const float*)d_in[34];
  const float* W_ps3 = (const float*)d_in[35];
  const float* b_ps3 = (const float*)d_in[36];
  const float* W_t = (const float*)d_in[37];

  const int N1 = in_sizes[4];
  const int N2 = in_sizes[5];

  // ---- workspace layout ----
  char* base = (char*)d_ws;
  size_t off = 0;
  auto alloc = [&](size_t bytes) -> void* {
    void* r = base + off;
    off += (bytes + 255) & ~(size_t)255;
    return r;
  };
  float* x = (float*)alloc((size_t)N1 * 192 * 4);        // fine features; aliased by cat_f32
  float* T = (float*)alloc((size_t)N1 * 256 * 4);        // trunk temps / t192
  float* Bq1 = T;
  float* Bq2 = T + (size_t)N1 * 64;
  float* Bq3 = T + (size_t)N1 * 128;
  float* Bq4 = T + (size_t)N1 * 192;
  float* t192 = T;
  u16* catb = (u16*)alloc((size_t)N2 * 192 * 2);
  u16* hb = (u16*)alloc((size_t)N2 * 192 * 2);
  u16* pib = (u16*)alloc((size_t)N2 * 192 * 2);
  u16* fullb = (u16*)alloc((size_t)N2 * 232 * 2);
  float* spf = (float*)alloc((size_t)N2 * 128 * 4);
  u16* WTpi1 = (u16*)alloc((size_t)27 * 192 * 192 * 2);
  u16* WTpi2 = (u16*)alloc((size_t)27 * 192 * 192 * 2);
  u16* WTps1 = (u16*)alloc((size_t)27 * 192 * 192 * 2);
  u16* WTps2 = (u16*)alloc((size_t)27 * 192 * 192 * 2);
  u16* WTpi3 = (u16*)alloc((size_t)27 * 32 * 192 * 2);
  u16* WTps3 = (u16*)alloc((size_t)27 * 32 * 192 * 2);
  u16* WTt = (u16*)alloc((size_t)8 * 64 * 256 * 2);
  float* stats = (float*)alloc((size_t)19 * 772 * 4);
  if (off > ws_size) return;  // workspace too small: bail (will fail loudly)

  float* catf = x;  // alias: x is dead once encoder residuals are built
  float* dout = (float*)d_out;
  float* out0 = dout;
  float* proxyp = dout + (size_t)N2 * 512;
  float* pip = proxyp + N2;
  float* psp = pip + (size_t)N2 * 17;

  hipMemsetAsync(stats, 0, (size_t)19 * 772 * 4, stream);

  // weight conversion for bf16 heads
  k_wconv<<<256, 256, 0, stream>>>(W_pi1, WTpi1, 27, 192, 192, 192, 192);
  k_wconv<<<256, 256, 0, stream>>>(W_pi2, WTpi2, 27, 192, 192, 192, 192);
  k_wconv<<<256, 256, 0, stream>>>(W_ps1, WTps1, 27, 192, 192, 192, 192);
  k_wconv<<<256, 256, 0, stream>>>(W_ps2, WTps2, 27, 192, 192, 192, 192);
  k_wconv<<<256, 256, 0, stream>>>(W_pi3, WTpi3, 27, 192, 17, 32, 192);
  k_wconv<<<256, 256, 0, stream>>>(W_ps3, WTps3, 27, 192, 20, 32, 192);
  k_wconv<<<256, 256, 0, stream>>>(W_t, WTt, 8, 229, 64, 64, 256);

  const int SG = 512;    // stats grid
  const int AG = 2048;   // apply grid
  int slot = 0;
  struct Br { int aoff, Cin; const float *W1, *W2, *Wd; };
  Br brs[3] = {{0, 2, W_d1, W_d2, Wd_d},
               {2, 80, W_f1, W_f2, Wd_f},
               {82, 17, W_i1, W_i2, Wd_i}};

  // ---- fine branches (fp32 trunk) ----
  for (int b = 0; b < 3; ++b) {
    // dense residual: inorm(f @ Wd)  (bias is a no-op under inorm)
    k1_conv<<<dim3(cdiv(N1, 64), 1), 256, 0, stream>>>(
        features, 99, brs[b].aoff, brs[b].Cin, nullptr, 1, brs[b].Wd, 64, nullptr, Bq1, 64, N1);
    k_stats<<<SG, 256, 0, stream>>>(Bq1, 64, N1, 64, b1, stats + slot * 772);
    k_apply<<<AG, 256, 0, stream>>>(Bq1, 64, N1, 64, b1, stats + slot * 772,
                                    nullptr, 0, 0, Bq3, 64, nullptr, 0);
    slot++;
    // conv1 + inorm + relu
    k1_conv<<<dim3(cdiv(N1, 64), 1), 256, 0, stream>>>(
        features, 99, brs[b].aoff, brs[b].Cin, nmap1, 27, brs[b].W1, 64, nullptr, Bq1, 64, N1);
    k_stats<<<SG, 256, 0, stream>>>(Bq1, 64, N1, 64, b1, stats + slot * 772);
    k_apply<<<AG, 256, 0, stream>>>(Bq1, 64, N1, 64, b1, stats + slot * 772,
                                    nullptr, 0, 1, Bq2, 64, nullptr, 0);
    slot++;
    // conv2 + inorm + res + relu  -> x[:, b*64 : b*64+64]
    k1_conv<<<dim3(cdiv(N1, 64), 1), 256, 0, stream>>>(
        Bq2, 64, 0, 64, nmap1, 27, brs[b].W2, 64, nullptr, Bq4, 64, N1);
    k_stats<<<SG, 256, 0, stream>>>(Bq4, 64, N1, 64, b1, stats + slot * 772);
    k_apply<<<AG, 256, 0, stream>>>(Bq4, 64, N1, 64, b1, stats + slot * 772,
                                    Bq3, 64, 1, x + b * 64, 192, nullptr, 0);
    slot++;
  }

  // ---- encoder (fp32 trunk) ----
  // e1a: downsample conv (cmap, K=8) + inorm + relu -> Bq2
  k1_conv<<<dim3(cdiv(N2, 64), 1), 256, 0, stream>>>(
      x, 192, 0, 192, cmap, 8, W_e1a, 64, nullptr, Bq1, 64, N2);
  k_stats<<<SG, 256, 0, stream>>>(Bq1, 64, N2, 64, b2, stats + slot * 772);
  k_apply<<<AG, 256, 0, stream>>>(Bq1, 64, N2, 64, b2, stats + slot * 772,
                                  nullptr, 0, 1, Bq2, 64, nullptr, 0);
  int sl_e1a = slot; slot++;
  // e1b conv -> Bq4 (norm applied later with res)
  k1_conv<<<dim3(cdiv(N2, 64), 1), 256, 0, stream>>>(
      Bq2, 64, 0, 64, nmap2, 27, W_e1b, 64, nullptr, Bq4, 64, N2);
  k_stats<<<SG, 256, 0, stream>>>(Bq4, 64, N2, 64, b2, stats + slot * 772);
  int sl_e1b = slot; slot++;
  // ed: residual downsample conv + inorm (b_ed no-op) -> Bq3
  k1_conv<<<dim3(cdiv(N2, 64), 1), 256, 0, stream>>>(
      x, 192, 0, 192, cmap, 8, W_ed, 64, nullptr, Bq1, 64, N2);
  k_stats<<<SG, 256, 0, stream>>>(Bq1, 64, N2, 64, b2, stats + slot * 772);
  k_apply<<<AG, 256, 0, stream>>>(Bq1, 64, N2, 64, b2, stats + slot * 772,
                                  nullptr, 0, 0, Bq3, 64, nullptr, 0);
  slot++;
  // enc_pre = relu(inorm(e1b) + res) -> Bq2
  k_apply<<<AG, 256, 0, stream>>>(Bq4, 64, N2, 64, b2, stats + sl_e1b * 772,
                                  Bq3, 64, 1, Bq2, 64, nullptr, 0);
  (void)sl_e1a;
  // _sbb(enc_pre): e2a conv + inorm + relu -> Bq3
  k1_conv<<<dim3(cdiv(N2, 64), 1), 256, 0, stream>>>(
      Bq2, 64, 0, 64, nmap2, 27, W_e2a, 64, nullptr, Bq1, 64, N2);
  k_stats<<<SG, 256, 0, stream>>>(Bq1, 64, N2, 64, b2, stats + slot * 772);
  k_apply<<<AG, 256, 0, stream>>>(Bq1, 64, N2, 64, b2, stats + slot * 772,
                                  nullptr, 0, 1, Bq3, 64, nullptr, 0);
  slot++;
  // e2b conv + inorm + res(enc_pre) + relu -> enc (cat cols 0..63, f32+bf16)
  k1_conv<<<dim3(cdiv(N2, 64), 1), 256, 0, stream>>>(
      Bq3, 64, 0, 64, nmap2, 27, W_e2b, 64, nullptr, Bq4, 64, N2);
  k_stats<<<SG, 256, 0, stream>>>(Bq4, 64, N2, 64, b2, stats + slot * 772);
  k_apply<<<AG, 256, 0, stream>>>(Bq4, 64, N2, 64, b2, stats + slot * 772,
                                  Bq2, 64, 1, catf, 192, catb, 192);
  slot++;

  // ---- sparse / proxy / mask (fp32) ----
  k1_conv<<<dim3(cdiv(N2, 64), 2), 256, 0, stream>>>(
      catf, 192, 0, 64, nullptr, 1, W_sub, 128, b_sub, spf, 128, N2);
  k_mask<<<cdiv(N2, 4), 256, 0, stream>>>(spf, W_occ, b_occ, proxyp, catf, catb, N2);
  k_full<<<1024, 256, 0, stream>>>(catb, fullb, N2);

  // ---- heads (bf16 MFMA) ----
  const u16* WT1[2] = {WTpi1, WTps1};
  const u16* WT2[2] = {WTpi2, WTps2};
  const u16* WT3[2] = {WTpi3, WTps3};
  const float* b3v[2] = {b_pi3, b_ps3};
  float* outh[2] = {pip, psp};
  int co3[2] = {17, 20};
  int ld3[2] = {17, 20};
  int foff[2] = {192, 209};
  for (int h = 0; h < 2; ++h) {
    k2_conv<<<cdiv(N2, 128), 256, 0, stream>>>(
        catb, 192, nmap2, 27, WT1[h], 192, 192, 192, nullptr, t192, 192, nullptr, 0, N2);
    k_stats<<<SG, 256, 0, stream>>>(t192, 192, N2, 192, b2, stats + slot * 772);
    k_apply<<<AG, 256, 0, stream>>>(t192, 192, N2, 192, b2, stats + slot * 772,
                                    nullptr, 0, 1, nullptr, 0, hb, 192);
    slot++;
    k2_conv<<<cdiv(N2, 128), 256, 0, stream>>>(
        hb, 192, nmap2, 27, WT2[h], 192, 192, 192, nullptr, t192, 192, nullptr, 0, N2);
    k_stats<<<SG, 256, 0, stream>>>(t192, 192, N2, 192, b2, stats + slot * 772);
    k_apply<<<AG, 256, 0, stream>>>(t192, 192, N2, 192, b2, stats + slot * 772,
                                    catf, 192, 1, nullptr, 0, pib, 192);
    slot++;
    k2_conv<<<cdiv(N2, 128), 256, 0, stream>>>(
        pib, 192, nmap2, 27, WT3[h], 32, 192, co3[h], b3v[h],
        outh[h], ld3[h], fullb + foff[h], 232, N2);
  }

  // ---- final einsum: out[m*8+k, :] = full[m] @ W_t[k] ----
  for (int k = 0; k < 8; ++k) {
    k2_conv<<<cdiv(N2, 128), 256, 0, stream>>>(
        fullb, 232, nullptr, 1, WTt + (size_t)k * 64 * 256, 64, 256, 64, nullptr,
        out0 + (size_t)k * 64, 512, nullptr, 0, N2);
  }
  // final inorm + relu over (N2*8, 64) rows with b3, in place in d_out
  k_stats<<<SG, 256, 0, stream>>>(out0, 64, N2 * 8, 64, b3, stats + slot * 772);
  k_apply<<<AG, 256, 0, stream>>>(out0, 64, N2 * 8, 64, b3, stats + slot * 772,
                                  nullptr, 0, 1, out0, 64, nullptr, 0);
}

// Round 2
// 8838.013 us; speedup vs baseline: 1.6494x; 1.6494x over previous
//
#include <hip/hip_runtime.h>

typedef unsigned short u16;
typedef unsigned int u32;
typedef __bf16 bf16x8 __attribute__((ext_vector_type(8)));
typedef float f32x4 __attribute__((ext_vector_type(4)));

__device__ __forceinline__ u16 f2bf(float f) {
  u32 u = __builtin_bit_cast(u32, f);
  u = (u + 0x7FFFu + ((u >> 16) & 1u)) >> 16;
  return (u16)u;
}

static inline int cdiv(int a, int b) { return (a + b - 1) / b; }

// ---------------------------------------------------------------------------
// K1: fp32 gathered sparse-conv / GEMM with register prefetch.
// out[m,co] = sum_k sum_ci A[nmap[m,k], aoff+ci] * W[k,ci,co].
// nmap==null -> identity.  Tile 64x64, BK=16, 256 thr, 4x4 per thread.
// ---------------------------------------------------------------------------
__global__ __launch_bounds__(256) void k1_conv(
    const float* __restrict__ A, int lda, int aoff, int Cin,
    const int* __restrict__ nmap, int K,
    const float* __restrict__ W, int Cout,
    const float* __restrict__ bias,
    float* __restrict__ out, int ldo, int M) {
  __shared__ float As[16][64];
  __shared__ float Ws[16][64];
  const int tid = threadIdx.x;
  const int m0 = blockIdx.x * 64;
  const int n0 = blockIdx.y * 64;
  const int tr = (tid >> 4) << 2;
  const int tc = (tid & 15) << 2;
  const int r = tid & 63;
  const int cb = (tid >> 6) << 2;
  const int CB = (Cin + 15) >> 4;
  float acc[4][4] = {{0.f}};
  float pa[4], pw[4];
  auto fetch = [&](int k, int cblk) {
    int c0 = cblk * 16;
    int m = m0 + r;
    int idx = (m < M) ? (nmap ? nmap[(long)m * K + k] : m) : -1;
    const float* src = A + (long)idx * lda + aoff + c0 + cb;
#pragma unroll
    for (int i = 0; i < 4; ++i) {
      int ci = c0 + cb + i;
      pa[i] = (idx >= 0 && ci < Cin) ? src[i] : 0.f;
    }
    const float* wsrc = W + ((long)k * Cin + c0 + cb) * Cout + n0 + r;
#pragma unroll
    for (int i = 0; i < 4; ++i) {
      int ci = c0 + cb + i;
      pw[i] = (ci < Cin) ? wsrc[(long)i * Cout] : 0.f;
    }
  };
  fetch(0, 0);
  int kc = 0, cc = 0;
  const int T = K * CB;
  for (int t = 0; t < T; ++t) {
#pragma unroll
    for (int i = 0; i < 4; ++i) As[cb + i][r] = pa[i];
#pragma unroll
    for (int i = 0; i < 4; ++i) Ws[cb + i][r] = pw[i];
    __syncthreads();
    int cn = cc + 1, kn = kc;
    if (cn == CB) { cn = 0; kn++; }
    if (kn < K) fetch(kn, cn);
#pragma unroll
    for (int kk = 0; kk < 16; ++kk) {
      float a[4], b[4];
#pragma unroll
      for (int i = 0; i < 4; ++i) a[i] = As[kk][tr + i];
#pragma unroll
      for (int j = 0; j < 4; ++j) b[j] = Ws[kk][tc + j];
#pragma unroll
      for (int i = 0; i < 4; ++i)
#pragma unroll
        for (int j = 0; j < 4; ++j) acc[i][j] += a[i] * b[j];
    }
    __syncthreads();
    cc = cn; kc = kn;
  }
#pragma unroll
  for (int i = 0; i < 4; ++i) {
    int m = m0 + tr + i;
    if (m >= M) continue;
#pragma unroll
    for (int j = 0; j < 4; ++j) {
      int co = n0 + tc + j;
      float v = acc[i][j];
      if (bias) v += bias[co];
      out[(long)m * ldo + co] = v;
    }
  }
}

// ---------------------------------------------------------------------------
// K2: bf16 MFMA gathered sparse-conv with register prefetch + N-tiling.
// A bf16 [*, lda]; WT bf16 pre-transposed [k][WTR][CP].
// Block tile 128 x 192 at col offset blockIdx.y*192; 4 waves, each wave
// 4 row-strips x 6 col-tiles of mfma_f32_16x16x32_bf16.
// ---------------------------------------------------------------------------
#define K2_SA 72
__global__ __launch_bounds__(256) void k2_conv(
    const u16* __restrict__ A, int lda,
    const int* __restrict__ nmap, int K,
    const u16* __restrict__ WT, int WTR, int CP,
    int Cout,
    const float* __restrict__ bias,
    float* __restrict__ of, int ldo,
    u16* __restrict__ ob, int ldb,
    int M) {
  __shared__ __align__(16) u16 As[128 * K2_SA];
  __shared__ __align__(16) u16 Ws[192 * K2_SA];
  const int tid = threadIdx.x;
  const int m0 = blockIdx.x * 128;
  const int n0 = blockIdx.y * 192;
  const int lane = tid & 63;
  const int w = tid >> 6;
  const int wr = w >> 1, wc = w & 1;
  const int ln = lane & 15, qd = lane >> 4;
  int Cb = Cout - n0; if (Cb > 192) Cb = 192;
  int NTT = (Cb + 15) >> 4;
  int NTw = NTT - wc * 6;
  if (NTw < 0) NTw = 0;
  if (NTw > 6) NTw = 6;
  const int NSB = CP >> 6;
  const int T = K * NSB;
  const int ar = tid & 127;   // A row owned by this thread
  const int as0 = tid >> 7;   // A slot base: slots as0 + 2*i

  uint4 pa[4], pw[6];
  auto fetch = [&](int k, int sb) {
    int m = m0 + ar;
    int idx = (m < M) ? (nmap ? nmap[(long)m * K + k] : m) : -1;
    const u16* src = A + (long)idx * lda + sb * 64;
#pragma unroll
    for (int i = 0; i < 4; ++i) {
      int s = as0 + 2 * i;
      int ci = sb * 64 + s * 8;
      uint4 v = make_uint4(0u, 0u, 0u, 0u);
      if (idx >= 0 && ci + 8 <= lda) v = *(const uint4*)(src + s * 8);
      pa[i] = v;
    }
    const u16* wk = WT + (long)k * WTR * CP + sb * 64;
#pragma unroll
    for (int i = 0; i < 6; ++i) {
      int id = tid + 256 * i;
      int co = id >> 3, s = id & 7;
      int cog = n0 + co;
      uint4 v = make_uint4(0u, 0u, 0u, 0u);
      if (cog < WTR) v = *(const uint4*)(wk + (long)cog * CP + s * 8);
      pw[i] = v;
    }
  };

  f32x4 acc[4][6];
  f32x4 zero = {0.f, 0.f, 0.f, 0.f};
#pragma unroll
  for (int i = 0; i < 4; ++i)
#pragma unroll
    for (int j = 0; j < 6; ++j) acc[i][j] = zero;

  fetch(0, 0);
  int kc = 0, sc = 0;
  for (int t = 0; t < T; ++t) {
#pragma unroll
    for (int i = 0; i < 4; ++i)
      *(uint4*)&As[ar * K2_SA + (as0 + 2 * i) * 8] = pa[i];
#pragma unroll
    for (int i = 0; i < 6; ++i) {
      int id = tid + 256 * i;
      *(uint4*)&Ws[(id >> 3) * K2_SA + (id & 7) * 8] = pw[i];
    }
    __syncthreads();
    int sn = sc + 1, kn = kc;
    if (sn == NSB) { sn = 0; kn++; }
    if (kn < K) fetch(kn, sn);
    if (NTw > 0) {
#pragma unroll
      for (int ch = 0; ch < 2; ++ch) {
        int koff = ch * 32 + qd * 8;
        bf16x8 a[4];
#pragma unroll
        for (int st = 0; st < 4; ++st)
          a[st] = *(const bf16x8*)&As[(wr * 64 + st * 16 + ln) * K2_SA + koff];
#pragma unroll
        for (int nt = 0; nt < 6; ++nt) {
          if (nt < NTw) {
            bf16x8 b = *(const bf16x8*)&Ws[(wc * 96 + nt * 16 + ln) * K2_SA + koff];
#pragma unroll
            for (int st = 0; st < 4; ++st)
              acc[st][nt] = __builtin_amdgcn_mfma_f32_16x16x32_bf16(a[st], b, acc[st][nt], 0, 0, 0);
          }
        }
      }
    }
    __syncthreads();
    sc = sn; kc = kn;
  }
#pragma unroll
  for (int nt = 0; nt < 6; ++nt) {
    if (nt >= NTw) continue;
    int col = n0 + wc * 96 + nt * 16 + ln;
    if (col >= Cout) continue;
    float bv = bias ? bias[col] : 0.f;
#pragma unroll
    for (int st = 0; st < 4; ++st) {
#pragma unroll
      for (int i = 0; i < 4; ++i) {
        int m = m0 + wr * 64 + st * 16 + qd * 4 + i;
        if (m < M) {
          float v = acc[st][nt][i] + bv;
          if (of) of[(long)m * ldo + col] = v;
          if (ob) ob[(long)m * ldb + col] = f2bf(v);
        }
      }
    }
  }
}

// ---------------------------------------------------------------------------
// stats: per-(batch,channel) sum / sumsq (+count) for instance norm.
// Vectorized: all threads active, float4 loads, LDS-atomic block reduce.
// slot layout: [sum0(C), sq0(C), sum1(C), sq1(C), cnt0, cnt1]
// ---------------------------------------------------------------------------
__global__ __launch_bounds__(256) void k_stats(
    const float* __restrict__ x, int ld, int M, int C,
    const int* __restrict__ bidx, float* __restrict__ st) {
  __shared__ float ssum[2][192];
  __shared__ float ssq[2][192];
  __shared__ float scnt[2];
  for (int i = threadIdx.x; i < 384; i += 256) {
    ((float*)ssum)[i] = 0.f;
    ((float*)ssq)[i] = 0.f;
  }
  if (threadIdx.x < 2) scnt[threadIdx.x] = 0.f;
  __syncthreads();
  const int CV = C >> 2;
  const int RG = 256 / CV;
  const int tid = threadIdx.x;
  const int c4 = tid % CV;
  const int rg = tid / CV;
  int rpb = (M + gridDim.x - 1) / gridDim.x;
  int r0 = blockIdx.x * rpb;
  int r1 = r0 + rpb;
  if (r1 > M) r1 = M;
  if (rg < RG) {
    float s0[4] = {0.f, 0.f, 0.f, 0.f}, q0[4] = {0.f, 0.f, 0.f, 0.f};
    float s1[4] = {0.f, 0.f, 0.f, 0.f}, q1[4] = {0.f, 0.f, 0.f, 0.f};
    float n0 = 0.f, n1 = 0.f;
    for (int rr = r0 + rg; rr < r1; rr += RG) {
      int b = bidx[rr];
      float4 v = *(const float4*)&x[(long)rr * ld + c4 * 4];
      const float* vp = &v.x;
      if (b == 0) {
#pragma unroll
        for (int j = 0; j < 4; ++j) { s0[j] += vp[j]; q0[j] += vp[j] * vp[j]; }
        n0 += 1.f;
      } else {
#pragma unroll
        for (int j = 0; j < 4; ++j) { s1[j] += vp[j]; q1[j] += vp[j] * vp[j]; }
        n1 += 1.f;
      }
    }
#pragma unroll
    for (int j = 0; j < 4; ++j) {
      if (s0[j] != 0.f || q0[j] != 0.f) {
        atomicAdd(&ssum[0][c4 * 4 + j], s0[j]);
        atomicAdd(&ssq[0][c4 * 4 + j], q0[j]);
      }
      if (s1[j] != 0.f || q1[j] != 0.f) {
        atomicAdd(&ssum[1][c4 * 4 + j], s1[j]);
        atomicAdd(&ssq[1][c4 * 4 + j], q1[j]);
      }
    }
    if (c4 == 0) {
      if (n0 != 0.f) atomicAdd(&scnt[0], n0);
      if (n1 != 0.f) atomicAdd(&scnt[1], n1);
    }
  }
  __syncthreads();
  for (int i = threadIdx.x; i < C; i += 256) {
    if (ssum[0][i] != 0.f || ssq[0][i] != 0.f) {
      atomicAdd(&st[i], ssum[0][i]);
      atomicAdd(&st[C + i], ssq[0][i]);
    }
    if (ssum[1][i] != 0.f || ssq[1][i] != 0.f) {
      atomicAdd(&st[2 * C + i], ssum[1][i]);
      atomicAdd(&st[3 * C + i], ssq[1][i]);
    }
  }
  if (threadIdx.x == 0) {
    if (scnt[0] != 0.f) atomicAdd(&st[4 * C], scnt[0]);
    if (scnt[1] != 0.f) atomicAdd(&st[4 * C + 1], scnt[1]);
  }
}

// ---------------------------------------------------------------------------
// apply: v = (x - mean)*rsqrt(var+eps) [+ res] [relu] -> optional f32 / bf16
// Vectorized float4.
// ---------------------------------------------------------------------------
__global__ __launch_bounds__(256) void k_apply(
    const float* __restrict__ x, int ldx, int M, int C,
    const int* __restrict__ bidx, const float* __restrict__ st,
    const float* __restrict__ res, int ldr, int relu,
    float* __restrict__ of, int ldo, u16* __restrict__ ob, int ldb) {
  __shared__ float mean_s[2][192];
  __shared__ float inv_s[2][192];
  for (int j = threadIdx.x; j < 2 * C; j += 256) {
    int b = (j >= C) ? 1 : 0;
    int c = j - b * C;
    float cnt = st[4 * C + b];
    float mean = st[b * 2 * C + c] / cnt;
    float var = st[b * 2 * C + C + c] / cnt - mean * mean;
    mean_s[b][c] = mean;
    inv_s[b][c] = 1.f / sqrtf(fmaxf(var, 0.f) + 1e-5f);
  }
  __syncthreads();
  const int CV = C >> 2;
  long total = (long)M * CV;
  long stride = (long)gridDim.x * 256;
  for (long i = (long)blockIdx.x * 256 + threadIdx.x; i < total; i += stride) {
    int rr = (int)(i / CV);
    int c4 = (int)(i - (long)rr * CV);
    int b = bidx[rr];
    float4 v = *(const float4*)&x[(long)rr * ldx + c4 * 4];
    const float* vp = &v.x;
    float o[4];
#pragma unroll
    for (int j = 0; j < 4; ++j) {
      int c = c4 * 4 + j;
      o[j] = (vp[j] - mean_s[b][c]) * inv_s[b][c];
    }
    if (res) {
      float4 rv = *(const float4*)&res[(long)rr * ldr + c4 * 4];
      const float* rp = &rv.x;
#pragma unroll
      for (int j = 0; j < 4; ++j) o[j] += rp[j];
    }
    if (relu) {
#pragma unroll
      for (int j = 0; j < 4; ++j) o[j] = fmaxf(o[j], 0.f);
    }
    if (of) {
      float4 ov = make_float4(o[0], o[1], o[2], o[3]);
      *(float4*)&of[(long)rr * ldo + c4 * 4] = ov;
    }
    if (ob) {
      ushort4 u;
      u.x = f2bf(o[0]); u.y = f2bf(o[1]); u.z = f2bf(o[2]); u.w = f2bf(o[3]);
      *(ushort4*)&ob[(long)rr * ldb + c4 * 4] = u;
    }
  }
}

// proxy = sparse @ W_occ + b_occ ; mask = proxy > 0 ; sp = mask ? sparse : 0
__global__ __launch_bounds__(256) void k_mask(
    const float* __restrict__ sp, const float* __restrict__ Wocc,
    const float* __restrict__ bocc, float* __restrict__ proxy,
    float* __restrict__ catf, u16* __restrict__ catb, int M) {
  int r = blockIdx.x * 4 + (threadIdx.x >> 6);
  int lane = threadIdx.x & 63;
  if (r >= M) return;
  float v0 = sp[(long)r * 128 + lane];
  float v1 = sp[(long)r * 128 + 64 + lane];
  float s = v0 * Wocc[lane] + v1 * Wocc[64 + lane];
  for (int off = 32; off > 0; off >>= 1) s += __shfl_down(s, off);
  s = __shfl(s, 0);
  float p = s + bocc[0];
  if (lane == 0) proxy[r] = p;
  bool m = p > 0.0f;
  float w0 = m ? v0 : 0.f, w1 = m ? v1 : 0.f;
  catf[(long)r * 192 + 64 + lane] = w0;
  catf[(long)r * 192 + 128 + lane] = w1;
  catb[(long)r * 192 + 64 + lane] = f2bf(w0);
  catb[(long)r * 192 + 128 + lane] = f2bf(w1);
}

// copy cat -> full[:,0:192] and zero full[:,229:232]
__global__ __launch_bounds__(256) void k_full(
    const u16* __restrict__ catb, u16* __restrict__ full, int M) {
  long total = (long)M * 195;
  long stride = (long)gridDim.x * 256;
  for (long i = (long)blockIdx.x * 256 + threadIdx.x; i < total; i += stride) {
    int r = (int)(i / 195);
    int j = (int)(i - (long)r * 195);
    if (j < 192)
      full[(long)r * 232 + j] = catb[(long)r * 192 + j];
    else
      full[(long)r * 232 + 229 + (j - 192)] = 0;
  }
}

// weight convert: src f32 [K][Cin][Cout] -> dst bf16 transposed [K][WTR][CP]
__global__ __launch_bounds__(256) void k_wconv(
    const float* __restrict__ src, u16* __restrict__ dst,
    int K, int Cin, int Cout, int WTR, int CP) {
  long total = (long)K * WTR * CP;
  long stride = (long)gridDim.x * 256;
  for (long i = (long)blockIdx.x * 256 + threadIdx.x; i < total; i += stride) {
    int ci = (int)(i % CP);
    long t = i / CP;
    int co = (int)(t % WTR);
    int k = (int)(t / WTR);
    float v = 0.f;
    if (ci < Cin && co < Cout) v = src[((long)k * Cin + ci) * Cout + co];
    dst[i] = f2bf(v);
  }
}

// ---------------------------------------------------------------------------
extern "C" void kernel_launch(void* const* d_in, const int* in_sizes, int n_in,
                              void* d_out, int out_size, void* d_ws, size_t ws_size,
                              hipStream_t stream) {
  const float* features = (const float*)d_in[0];
  const int* nmap1 = (const int*)d_in[1];
  const int* cmap = (const int*)d_in[2];
  const int* nmap2 = (const int*)d_in[3];
  const int* b1 = (const int*)d_in[4];
  const int* b2 = (const int*)d_in[5];
  const int* b3 = (const int*)d_in[6];
  const float* W_d1 = (const float*)d_in[7];
  const float* W_d2 = (const float*)d_in[8];
  const float* Wd_d = (const float*)d_in[9];
  const float* W_f1 = (const float*)d_in[11];
  const float* W_f2 = (const float*)d_in[12];
  const float* Wd_f = (const float*)d_in[13];
  const float* W_i1 = (const float*)d_in[15];
  const float* W_i2 = (const float*)d_in[16];
  const float* Wd_i = (const float*)d_in[17];
  const float* W_e1a = (const float*)d_in[19];
  const float* W_e1b = (const float*)d_in[20];
  const float* W_ed = (const float*)d_in[21];
  const float* W_e2a = (const float*)d_in[23];
  const float* W_e2b = (const float*)d_in[24];
  const float* W_sub = (const float*)d_in[25];
  const float* b_sub = (const float*)d_in[26];
  const float* W_occ = (const float*)d_in[27];
  const float* b_occ = (const float*)d_in[28];
  const float* W_pi1 = (const float*)d_in[29];
  const float* W_pi2 = (const float*)d_in[30];
  const float* W_pi3 = (const float*)d_in[31];
  const float* b_pi3 = (const float*)d_in[32];
  const float* W_ps1 = (const float*)d_in[33];
  const float* W_ps2 = (const float*)d_in[34];
  const float* W_ps3 = (const float*)d_in[35];
  const float* b_ps3 = (const float*)d_in[36];
  const float* W_t = (const float*)d_in[37];

  const int N1 = in_sizes[4];
  const int N2 = in_sizes[5];

  // ---- workspace layout ----
  char* base = (char*)d_ws;
  size_t off = 0;
  auto alloc = [&](size_t bytes) -> void* {
    void* r = base + off;
    off += (bytes + 255) & ~(size_t)255;
    return r;
  };
  float* x = (float*)alloc((size_t)N1 * 192 * 4);        // fine features; aliased by cat_f32
  float* T = (float*)alloc((size_t)N1 * 256 * 4);        // trunk temps / t192
  float* Bq1 = T;
  float* Bq2 = T + (size_t)N1 * 64;
  float* Bq3 = T + (size_t)N1 * 128;
  float* Bq4 = T + (size_t)N1 * 192;
  float* t192 = T;
  u16* catb = (u16*)alloc((size_t)N2 * 192 * 2);
  u16* hb = (u16*)alloc((size_t)N2 * 192 * 2);
  u16* pib = (u16*)alloc((size_t)N2 * 192 * 2);
  u16* fullb = (u16*)alloc((size_t)N2 * 232 * 2);
  float* spf = (float*)alloc((size_t)N2 * 128 * 4);
  u16* WTpi1 = (u16*)alloc((size_t)27 * 192 * 192 * 2);
  u16* WTpi2 = (u16*)alloc((size_t)27 * 192 * 192 * 2);
  u16* WTps1 = (u16*)alloc((size_t)27 * 192 * 192 * 2);
  u16* WTps2 = (u16*)alloc((size_t)27 * 192 * 192 * 2);
  u16* WTpi3 = (u16*)alloc((size_t)27 * 32 * 192 * 2);
  u16* WTps3 = (u16*)alloc((size_t)27 * 32 * 192 * 2);
  u16* WTt = (u16*)alloc((size_t)8 * 64 * 256 * 2);
  float* stats = (float*)alloc((size_t)19 * 772 * 4);
  if (off > ws_size) return;  // workspace too small: bail (will fail loudly)

  float* catf = x;  // alias: x is dead once encoder residuals are built
  float* dout = (float*)d_out;
  float* out0 = dout;
  float* proxyp = dout + (size_t)N2 * 512;
  float* pip = proxyp + N2;
  float* psp = pip + (size_t)N2 * 17;

  hipMemsetAsync(stats, 0, (size_t)19 * 772 * 4, stream);

  // weight conversion for bf16 heads
  k_wconv<<<256, 256, 0, stream>>>(W_pi1, WTpi1, 27, 192, 192, 192, 192);
  k_wconv<<<256, 256, 0, stream>>>(W_pi2, WTpi2, 27, 192, 192, 192, 192);
  k_wconv<<<256, 256, 0, stream>>>(W_ps1, WTps1, 27, 192, 192, 192, 192);
  k_wconv<<<256, 256, 0, stream>>>(W_ps2, WTps2, 27, 192, 192, 192, 192);
  k_wconv<<<256, 256, 0, stream>>>(W_pi3, WTpi3, 27, 192, 17, 32, 192);
  k_wconv<<<256, 256, 0, stream>>>(W_ps3, WTps3, 27, 192, 20, 32, 192);
  k_wconv<<<256, 256, 0, stream>>>(W_t, WTt, 8, 229, 64, 64, 256);

  const int SG = 1024;   // stats grid
  const int AG = 1024;   // apply grid
  int slot = 0;
  struct Br { int aoff, Cin; const float *W1, *W2, *Wd; };
  Br brs[3] = {{0, 2, W_d1, W_d2, Wd_d},
               {2, 80, W_f1, W_f2, Wd_f},
               {82, 17, W_i1, W_i2, Wd_i}};

  // ---- fine branches (fp32 trunk) ----
  for (int b = 0; b < 3; ++b) {
    // dense residual: inorm(f @ Wd)  (bias is a no-op under inorm)
    k1_conv<<<dim3(cdiv(N1, 64), 1), 256, 0, stream>>>(
        features, 99, brs[b].aoff, brs[b].Cin, nullptr, 1, brs[b].Wd, 64, nullptr, Bq1, 64, N1);
    k_stats<<<SG, 256, 0, stream>>>(Bq1, 64, N1, 64, b1, stats + slot * 772);
    k_apply<<<AG, 256, 0, stream>>>(Bq1, 64, N1, 64, b1, stats + slot * 772,
                                    nullptr, 0, 0, Bq3, 64, nullptr, 0);
    slot++;
    // conv1 + inorm + relu
    k1_conv<<<dim3(cdiv(N1, 64), 1), 256, 0, stream>>>(
        features, 99, brs[b].aoff, brs[b].Cin, nmap1, 27, brs[b].W1, 64, nullptr, Bq1, 64, N1);
    k_stats<<<SG, 256, 0, stream>>>(Bq1, 64, N1, 64, b1, stats + slot * 772);
    k_apply<<<AG, 256, 0, stream>>>(Bq1, 64, N1, 64, b1, stats + slot * 772,
                                    nullptr, 0, 1, Bq2, 64, nullptr, 0);
    slot++;
    // conv2 + inorm + res + relu  -> x[:, b*64 : b*64+64]
    k1_conv<<<dim3(cdiv(N1, 64), 1), 256, 0, stream>>>(
        Bq2, 64, 0, 64, nmap1, 27, brs[b].W2, 64, nullptr, Bq4, 64, N1);
    k_stats<<<SG, 256, 0, stream>>>(Bq4, 64, N1, 64, b1, stats + slot * 772);
    k_apply<<<AG, 256, 0, stream>>>(Bq4, 64, N1, 64, b1, stats + slot * 772,
                                    Bq3, 64, 1, x + b * 64, 192, nullptr, 0);
    slot++;
  }

  // ---- encoder (fp32 trunk) ----
  // e1a: downsample conv (cmap, K=8) + inorm + relu -> Bq2
  k1_conv<<<dim3(cdiv(N2, 64), 1), 256, 0, stream>>>(
      x, 192, 0, 192, cmap, 8, W_e1a, 64, nullptr, Bq1, 64, N2);
  k_stats<<<SG, 256, 0, stream>>>(Bq1, 64, N2, 64, b2, stats + slot * 772);
  k_apply<<<AG, 256, 0, stream>>>(Bq1, 64, N2, 64, b2, stats + slot * 772,
                                  nullptr, 0, 1, Bq2, 64, nullptr, 0);
  slot++;
  // e1b conv -> Bq4 (norm applied later with res)
  k1_conv<<<dim3(cdiv(N2, 64), 1), 256, 0, stream>>>(
      Bq2, 64, 0, 64, nmap2, 27, W_e1b, 64, nullptr, Bq4, 64, N2);
  k_stats<<<SG, 256, 0, stream>>>(Bq4, 64, N2, 64, b2, stats + slot * 772);
  int sl_e1b = slot; slot++;
  // ed: residual downsample conv + inorm (b_ed no-op) -> Bq3
  k1_conv<<<dim3(cdiv(N2, 64), 1), 256, 0, stream>>>(
      x, 192, 0, 192, cmap, 8, W_ed, 64, nullptr, Bq1, 64, N2);
  k_stats<<<SG, 256, 0, stream>>>(Bq1, 64, N2, 64, b2, stats + slot * 772);
  k_apply<<<AG, 256, 0, stream>>>(Bq1, 64, N2, 64, b2, stats + slot * 772,
                                  nullptr, 0, 0, Bq3, 64, nullptr, 0);
  slot++;
  // enc_pre = relu(inorm(e1b) + res) -> Bq2
  k_apply<<<AG, 256, 0, stream>>>(Bq4, 64, N2, 64, b2, stats + sl_e1b * 772,
                                  Bq3, 64, 1, Bq2, 64, nullptr, 0);
  // _sbb(enc_pre): e2a conv + inorm + relu -> Bq3
  k1_conv<<<dim3(cdiv(N2, 64), 1), 256, 0, stream>>>(
      Bq2, 64, 0, 64, nmap2, 27, W_e2a, 64, nullptr, Bq1, 64, N2);
  k_stats<<<SG, 256, 0, stream>>>(Bq1, 64, N2, 64, b2, stats + slot * 772);
  k_apply<<<AG, 256, 0, stream>>>(Bq1, 64, N2, 64, b2, stats + slot * 772,
                                  nullptr, 0, 1, Bq3, 64, nullptr, 0);
  slot++;
  // e2b conv + inorm + res(enc_pre) + relu -> enc (cat cols 0..63, f32+bf16)
  k1_conv<<<dim3(cdiv(N2, 64), 1), 256, 0, stream>>>(
      Bq3, 64, 0, 64, nmap2, 27, W_e2b, 64, nullptr, Bq4, 64, N2);
  k_stats<<<SG, 256, 0, stream>>>(Bq4, 64, N2, 64, b2, stats + slot * 772);
  k_apply<<<AG, 256, 0, stream>>>(Bq4, 64, N2, 64, b2, stats + slot * 772,
                                  Bq2, 64, 1, catf, 192, catb, 192);
  slot++;

  // ---- sparse / proxy / mask (fp32) ----
  k1_conv<<<dim3(cdiv(N2, 64), 2), 256, 0, stream>>>(
      catf, 192, 0, 64, nullptr, 1, W_sub, 128, b_sub, spf, 128, N2);
  k_mask<<<cdiv(N2, 4), 256, 0, stream>>>(spf, W_occ, b_occ, proxyp, catf, catb, N2);
  k_full<<<1024, 256, 0, stream>>>(catb, fullb, N2);

  // ---- heads (bf16 MFMA) ----
  const u16* WT1[2] = {WTpi1, WTps1};
  const u16* WT2[2] = {WTpi2, WTps2};
  const u16* WT3[2] = {WTpi3, WTps3};
  const float* b3v[2] = {b_pi3, b_ps3};
  float* outh[2] = {pip, psp};
  int co3[2] = {17, 20};
  int ld3[2] = {17, 20};
  int foff[2] = {192, 209};
  for (int h = 0; h < 2; ++h) {
    k2_conv<<<dim3(cdiv(N2, 128), 1), 256, 0, stream>>>(
        catb, 192, nmap2, 27, WT1[h], 192, 192, 192, nullptr, t192, 192, nullptr, 0, N2);
    k_stats<<<SG, 256, 0, stream>>>(t192, 192, N2, 192, b2, stats + slot * 772);
    k_apply<<<AG, 256, 0, stream>>>(t192, 192, N2, 192, b2, stats + slot * 772,
                                    nullptr, 0, 1, nullptr, 0, hb, 192);
    slot++;
    k2_conv<<<dim3(cdiv(N2, 128), 1), 256, 0, stream>>>(
        hb, 192, nmap2, 27, WT2[h], 192, 192, 192, nullptr, t192, 192, nullptr, 0, N2);
    k_stats<<<SG, 256, 0, stream>>>(t192, 192, N2, 192, b2, stats + slot * 772);
    k_apply<<<AG, 256, 0, stream>>>(t192, 192, N2, 192, b2, stats + slot * 772,
                                    catf, 192, 1, nullptr, 0, pib, 192);
    slot++;
    k2_conv<<<dim3(cdiv(N2, 128), 1), 256, 0, stream>>>(
        pib, 192, nmap2, 27, WT3[h], 32, 192, co3[h], b3v[h],
        outh[h], ld3[h], fullb + foff[h], 232, N2);
  }

  // ---- final einsum as ONE GEMM: out[m, k*64+co] = full[m] . W_t[k][:,co] ----
  // WTt layout [8][64][256] flattened == [512][256] with row r = k*64+co;
  // out row-major [M,512] matches out[(m*8+k)*64+co].
  k2_conv<<<dim3(cdiv(N2, 128), 3), 256, 0, stream>>>(
      fullb, 232, nullptr, 1, WTt, 512, 256, 512, nullptr,
      out0, 512, nullptr, 0, N2);

  // final inorm + relu over (N2*8, 64) rows with b3, in place in d_out
  k_stats<<<SG, 256, 0, stream>>>(out0, 64, N2 * 8, 64, b3, stats + slot * 772);
  k_apply<<<AG, 256, 0, stream>>>(out0, 64, N2 * 8, 64, b3, stats + slot * 772,
                                  nullptr, 0, 1, out0, 64, nullptr, 0);
}

// Round 3
// 8794.417 us; speedup vs baseline: 1.6576x; 1.0050x over previous
//
#include <hip/hip_runtime.h>

typedef unsigned short u16;
typedef unsigned int u32;
typedef __bf16 bf16x8 __attribute__((ext_vector_type(8)));
typedef float f32x4 __attribute__((ext_vector_type(4)));

__device__ __forceinline__ u16 f2bf(float f) {
  u32 u = __builtin_bit_cast(u32, f);
  u = (u + 0x7FFFu + ((u >> 16) & 1u)) >> 16;
  return (u16)u;
}

static inline int cdiv(int a, int b) { return (a + b - 1) / b; }

// ---------------------------------------------------------------------------
// K1: fp32 gathered sparse-conv / GEMM with register prefetch.
// out[m,co] = sum_k sum_ci A[nmap[m,k], aoff+ci] * W[k,ci,co].
// nmap==null -> identity.  Tile 128x64, BK=16, 256 thr, 8x4 per thread.
// vec!=0 promises lda%4==0 && aoff%4==0 (float4 A loads legal).
// ---------------------------------------------------------------------------
__global__ __launch_bounds__(256) void k1_conv(
    const float* __restrict__ A, int lda, int aoff, int Cin,
    const int* __restrict__ nmap, int K,
    const float* __restrict__ W, int Cout,
    const float* __restrict__ bias,
    float* __restrict__ out, int ldo, int M, int vec) {
  __shared__ float As[16][128];
  __shared__ float Ws[16][64];
  const int tid = threadIdx.x;
  const int m0 = blockIdx.x * 128;
  const int n0 = blockIdx.y * 64;
  const int tr = (tid >> 4) << 3;   // row frag base 0..120
  const int tc = (tid & 15) << 2;   // col frag base 0..60
  const int r2 = tid & 127;         // staged A row
  const int half = tid >> 7;        // ci half (0/1) -> 8 elems
  const int cw = tid & 63;          // staged W col
  const int cbw = (tid >> 6) << 2;  // staged W ci base
  const int CB = (Cin + 15) >> 4;
  float acc[8][4] = {{0.f}};
  float pa[8], pw[4];
  auto fetch = [&](int k, int cblk) {
    int c0 = cblk * 16;
    int m = m0 + r2;
    int idx = (m < M) ? (nmap ? nmap[(long)m * K + k] : m) : -1;
    const float* src = A + (long)idx * lda + aoff + c0 + half * 8;
    if (vec && idx >= 0 && c0 + half * 8 + 8 <= Cin) {
      float4 v0 = *(const float4*)(src);
      float4 v1 = *(const float4*)(src + 4);
      pa[0] = v0.x; pa[1] = v0.y; pa[2] = v0.z; pa[3] = v0.w;
      pa[4] = v1.x; pa[5] = v1.y; pa[6] = v1.z; pa[7] = v1.w;
    } else {
#pragma unroll
      for (int i = 0; i < 8; ++i) {
        int ci = c0 + half * 8 + i;
        pa[i] = (idx >= 0 && ci < Cin) ? src[i] : 0.f;
      }
    }
    const float* wsrc = W + ((long)k * Cin + c0 + cbw) * Cout + n0 + cw;
#pragma unroll
    for (int i = 0; i < 4; ++i) {
      int ci = c0 + cbw + i;
      pw[i] = (ci < Cin) ? wsrc[(long)i * Cout] : 0.f;
    }
  };
  fetch(0, 0);
  int kc = 0, cc = 0;
  const int T = K * CB;
  for (int t = 0; t < T; ++t) {
#pragma unroll
    for (int i = 0; i < 8; ++i) As[half * 8 + i][r2] = pa[i];
#pragma unroll
    for (int i = 0; i < 4; ++i) Ws[cbw + i][cw] = pw[i];
    __syncthreads();
    int cn = cc + 1, kn = kc;
    if (cn == CB) { cn = 0; kn++; }
    if (kn < K) fetch(kn, cn);
#pragma unroll
    for (int kk = 0; kk < 16; ++kk) {
      float a[8], b[4];
#pragma unroll
      for (int i = 0; i < 8; ++i) a[i] = As[kk][tr + i];
#pragma unroll
      for (int j = 0; j < 4; ++j) b[j] = Ws[kk][tc + j];
#pragma unroll
      for (int i = 0; i < 8; ++i)
#pragma unroll
        for (int j = 0; j < 4; ++j) acc[i][j] += a[i] * b[j];
    }
    __syncthreads();
    cc = cn; kc = kn;
  }
#pragma unroll
  for (int i = 0; i < 8; ++i) {
    int m = m0 + tr + i;
    if (m >= M) continue;
#pragma unroll
    for (int j = 0; j < 4; ++j) {
      int co = n0 + tc + j;
      float v = acc[i][j];
      if (bias) v += bias[co];
      out[(long)m * ldo + co] = v;
    }
  }
}

// ---------------------------------------------------------------------------
// K2: bf16 MFMA gathered sparse-conv with register prefetch + N-tiling.
// A bf16 [*, lda]; WT bf16 pre-transposed [k][WTR][CP].
// Block tile 128 x 192 at col offset blockIdx.y*192; 4 waves, each wave
// 4 row-strips x 6 col-tiles of mfma_f32_16x16x32_bf16.
// ---------------------------------------------------------------------------
#define K2_SA 72
__global__ __launch_bounds__(256) void k2_conv(
    const u16* __restrict__ A, int lda,
    const int* __restrict__ nmap, int K,
    const u16* __restrict__ WT, int WTR, int CP,
    int Cout,
    const float* __restrict__ bias,
    float* __restrict__ of, int ldo,
    u16* __restrict__ ob, int ldb,
    int M) {
  __shared__ __align__(16) u16 As[128 * K2_SA];
  __shared__ __align__(16) u16 Ws[192 * K2_SA];
  const int tid = threadIdx.x;
  const int m0 = blockIdx.x * 128;
  const int n0 = blockIdx.y * 192;
  const int lane = tid & 63;
  const int w = tid >> 6;
  const int wr = w >> 1, wc = w & 1;
  const int ln = lane & 15, qd = lane >> 4;
  int Cb = Cout - n0; if (Cb > 192) Cb = 192;
  int NTT = (Cb + 15) >> 4;
  int NTw = NTT - wc * 6;
  if (NTw < 0) NTw = 0;
  if (NTw > 6) NTw = 6;
  const int NSB = CP >> 6;
  const int T = K * NSB;
  const int ar = tid & 127;   // A row owned by this thread
  const int as0 = tid >> 7;   // A slot base: slots as0 + 2*i

  uint4 pa[4], pw[6];
  auto fetch = [&](int k, int sb) {
    int m = m0 + ar;
    int idx = (m < M) ? (nmap ? nmap[(long)m * K + k] : m) : -1;
    const u16* src = A + (long)idx * lda + sb * 64;
#pragma unroll
    for (int i = 0; i < 4; ++i) {
      int s = as0 + 2 * i;
      int ci = sb * 64 + s * 8;
      uint4 v = make_uint4(0u, 0u, 0u, 0u);
      if (idx >= 0 && ci + 8 <= lda) v = *(const uint4*)(src + s * 8);
      pa[i] = v;
    }
    const u16* wk = WT + (long)k * WTR * CP + sb * 64;
#pragma unroll
    for (int i = 0; i < 6; ++i) {
      int id = tid + 256 * i;
      int co = id >> 3, s = id & 7;
      int cog = n0 + co;
      uint4 v = make_uint4(0u, 0u, 0u, 0u);
      if (cog < WTR) v = *(const uint4*)(wk + (long)cog * CP + s * 8);
      pw[i] = v;
    }
  };

  f32x4 acc[4][6];
  f32x4 zero = {0.f, 0.f, 0.f, 0.f};
#pragma unroll
  for (int i = 0; i < 4; ++i)
#pragma unroll
    for (int j = 0; j < 6; ++j) acc[i][j] = zero;

  fetch(0, 0);
  int kc = 0, sc = 0;
  for (int t = 0; t < T; ++t) {
#pragma unroll
    for (int i = 0; i < 4; ++i)
      *(uint4*)&As[ar * K2_SA + (as0 + 2 * i) * 8] = pa[i];
#pragma unroll
    for (int i = 0; i < 6; ++i) {
      int id = tid + 256 * i;
      *(uint4*)&Ws[(id >> 3) * K2_SA + (id & 7) * 8] = pw[i];
    }
    __syncthreads();
    int sn = sc + 1, kn = kc;
    if (sn == NSB) { sn = 0; kn++; }
    if (kn < K) fetch(kn, sn);
    if (NTw > 0) {
#pragma unroll
      for (int ch = 0; ch < 2; ++ch) {
        int koff = ch * 32 + qd * 8;
        bf16x8 a[4];
#pragma unroll
        for (int st = 0; st < 4; ++st)
          a[st] = *(const bf16x8*)&As[(wr * 64 + st * 16 + ln) * K2_SA + koff];
#pragma unroll
        for (int nt = 0; nt < 6; ++nt) {
          if (nt < NTw) {
            bf16x8 b = *(const bf16x8*)&Ws[(wc * 96 + nt * 16 + ln) * K2_SA + koff];
#pragma unroll
            for (int st = 0; st < 4; ++st)
              acc[st][nt] = __builtin_amdgcn_mfma_f32_16x16x32_bf16(a[st], b, acc[st][nt], 0, 0, 0);
          }
        }
      }
    }
    __syncthreads();
    sc = sn; kc = kn;
  }
#pragma unroll
  for (int nt = 0; nt < 6; ++nt) {
    if (nt >= NTw) continue;
    int col = n0 + wc * 96 + nt * 16 + ln;
    if (col >= Cout) continue;
    float bv = bias ? bias[col] : 0.f;
#pragma unroll
    for (int st = 0; st < 4; ++st) {
#pragma unroll
      for (int i = 0; i < 4; ++i) {
        int m = m0 + wr * 64 + st * 16 + qd * 4 + i;
        if (m < M) {
          float v = acc[st][nt][i] + bv;
          if (of) of[(long)m * ldo + col] = v;
          if (ob) ob[(long)m * ldb + col] = f2bf(v);
        }
      }
    }
  }
}

// ---------------------------------------------------------------------------
// stats: per-(batch,channel) sum / sumsq (+count) for instance norm.
// Vectorized: all threads active, float4 loads, LDS-atomic block reduce.
// slot layout: [sum0(C), sq0(C), sum1(C), sq1(C), cnt0, cnt1]
// ---------------------------------------------------------------------------
__global__ __launch_bounds__(256) void k_stats(
    const float* __restrict__ x, int ld, int M, int C,
    const int* __restrict__ bidx, float* __restrict__ st) {
  __shared__ float ssum[2][192];
  __shared__ float ssq[2][192];
  __shared__ float scnt[2];
  for (int i = threadIdx.x; i < 384; i += 256) {
    ((float*)ssum)[i] = 0.f;
    ((float*)ssq)[i] = 0.f;
  }
  if (threadIdx.x < 2) scnt[threadIdx.x] = 0.f;
  __syncthreads();
  const int CV = C >> 2;
  const int RG = 256 / CV;
  const int tid = threadIdx.x;
  const int c4 = tid % CV;
  const int rg = tid / CV;
  int rpb = (M + gridDim.x - 1) / gridDim.x;
  int r0 = blockIdx.x * rpb;
  int r1 = r0 + rpb;
  if (r1 > M) r1 = M;
  if (rg < RG) {
    float s0[4] = {0.f, 0.f, 0.f, 0.f}, q0[4] = {0.f, 0.f, 0.f, 0.f};
    float s1[4] = {0.f, 0.f, 0.f, 0.f}, q1[4] = {0.f, 0.f, 0.f, 0.f};
    float n0 = 0.f, n1 = 0.f;
    for (int rr = r0 + rg; rr < r1; rr += RG) {
      int b = bidx[rr];
      float4 v = *(const float4*)&x[(long)rr * ld + c4 * 4];
      const float* vp = &v.x;
      if (b == 0) {
#pragma unroll
        for (int j = 0; j < 4; ++j) { s0[j] += vp[j]; q0[j] += vp[j] * vp[j]; }
        n0 += 1.f;
      } else {
#pragma unroll
        for (int j = 0; j < 4; ++j) { s1[j] += vp[j]; q1[j] += vp[j] * vp[j]; }
        n1 += 1.f;
      }
    }
#pragma unroll
    for (int j = 0; j < 4; ++j) {
      if (s0[j] != 0.f || q0[j] != 0.f) {
        atomicAdd(&ssum[0][c4 * 4 + j], s0[j]);
        atomicAdd(&ssq[0][c4 * 4 + j], q0[j]);
      }
      if (s1[j] != 0.f || q1[j] != 0.f) {
        atomicAdd(&ssum[1][c4 * 4 + j], s1[j]);
        atomicAdd(&ssq[1][c4 * 4 + j], q1[j]);
      }
    }
    if (c4 == 0) {
      if (n0 != 0.f) atomicAdd(&scnt[0], n0);
      if (n1 != 0.f) atomicAdd(&scnt[1], n1);
    }
  }
  __syncthreads();
  for (int i = threadIdx.x; i < C; i += 256) {
    if (ssum[0][i] != 0.f || ssq[0][i] != 0.f) {
      atomicAdd(&st[i], ssum[0][i]);
      atomicAdd(&st[C + i], ssq[0][i]);
    }
    if (ssum[1][i] != 0.f || ssq[1][i] != 0.f) {
      atomicAdd(&st[2 * C + i], ssum[1][i]);
      atomicAdd(&st[3 * C + i], ssq[1][i]);
    }
  }
  if (threadIdx.x == 0) {
    if (scnt[0] != 0.f) atomicAdd(&st[4 * C], scnt[0]);
    if (scnt[1] != 0.f) atomicAdd(&st[4 * C + 1], scnt[1]);
  }
}

// ---------------------------------------------------------------------------
// apply: v = (x - mean)*rsqrt(var+eps) [+ res] [relu] -> optional f32 / bf16
// Vectorized float4.
// ---------------------------------------------------------------------------
__global__ __launch_bounds__(256) void k_apply(
    const float* __restrict__ x, int ldx, int M, int C,
    const int* __restrict__ bidx, const float* __restrict__ st,
    const float* __restrict__ res, int ldr, int relu,
    float* __restrict__ of, int ldo, u16* __restrict__ ob, int ldb) {
  __shared__ float mean_s[2][192];
  __shared__ float inv_s[2][192];
  for (int j = threadIdx.x; j < 2 * C; j += 256) {
    int b = (j >= C) ? 1 : 0;
    int c = j - b * C;
    float cnt = st[4 * C + b];
    float mean = st[b * 2 * C + c] / cnt;
    float var = st[b * 2 * C + C + c] / cnt - mean * mean;
    mean_s[b][c] = mean;
    inv_s[b][c] = 1.f / sqrtf(fmaxf(var, 0.f) + 1e-5f);
  }
  __syncthreads();
  const int CV = C >> 2;
  long total = (long)M * CV;
  long stride = (long)gridDim.x * 256;
  for (long i = (long)blockIdx.x * 256 + threadIdx.x; i < total; i += stride) {
    int rr = (int)(i / CV);
    int c4 = (int)(i - (long)rr * CV);
    int b = bidx[rr];
    float4 v = *(const float4*)&x[(long)rr * ldx + c4 * 4];
    const float* vp = &v.x;
    float o[4];
#pragma unroll
    for (int j = 0; j < 4; ++j) {
      int c = c4 * 4 + j;
      o[j] = (vp[j] - mean_s[b][c]) * inv_s[b][c];
    }
    if (res) {
      float4 rv = *(const float4*)&res[(long)rr * ldr + c4 * 4];
      const float* rp = &rv.x;
#pragma unroll
      for (int j = 0; j < 4; ++j) o[j] += rp[j];
    }
    if (relu) {
#pragma unroll
      for (int j = 0; j < 4; ++j) o[j] = fmaxf(o[j], 0.f);
    }
    if (of) {
      float4 ov = make_float4(o[0], o[1], o[2], o[3]);
      *(float4*)&of[(long)rr * ldo + c4 * 4] = ov;
    }
    if (ob) {
      ushort4 u;
      u.x = f2bf(o[0]); u.y = f2bf(o[1]); u.z = f2bf(o[2]); u.w = f2bf(o[3]);
      *(ushort4*)&ob[(long)rr * ldb + c4 * 4] = u;
    }
  }
}

// proxy = sparse @ W_occ + b_occ ; mask = proxy > 0 ; sp = mask ? sparse : 0
__global__ __launch_bounds__(256) void k_mask(
    const float* __restrict__ sp, const float* __restrict__ Wocc,
    const float* __restrict__ bocc, float* __restrict__ proxy,
    float* __restrict__ catf, u16* __restrict__ catb, int M) {
  int r = blockIdx.x * 4 + (threadIdx.x >> 6);
  int lane = threadIdx.x & 63;
  if (r >= M) return;
  float v0 = sp[(long)r * 128 + lane];
  float v1 = sp[(long)r * 128 + 64 + lane];
  float s = v0 * Wocc[lane] + v1 * Wocc[64 + lane];
  for (int off = 32; off > 0; off >>= 1) s += __shfl_down(s, off);
  s = __shfl(s, 0);
  float p = s + bocc[0];
  if (lane == 0) proxy[r] = p;
  bool m = p > 0.0f;
  float w0 = m ? v0 : 0.f, w1 = m ? v1 : 0.f;
  catf[(long)r * 192 + 64 + lane] = w0;
  catf[(long)r * 192 + 128 + lane] = w1;
  catb[(long)r * 192 + 64 + lane] = f2bf(w0);
  catb[(long)r * 192 + 128 + lane] = f2bf(w1);
}

// copy cat -> full[:,0:192] and zero full[:,229:232]
__global__ __launch_bounds__(256) void k_full(
    const u16* __restrict__ catb, u16* __restrict__ full, int M) {
  long total = (long)M * 195;
  long stride = (long)gridDim.x * 256;
  for (long i = (long)blockIdx.x * 256 + threadIdx.x; i < total; i += stride) {
    int r = (int)(i / 195);
    int j = (int)(i - (long)r * 195);
    if (j < 192)
      full[(long)r * 232 + j] = catb[(long)r * 192 + j];
    else
      full[(long)r * 232 + 229 + (j - 192)] = 0;
  }
}

// weight convert: src f32 [K][Cin][Cout] -> dst bf16 transposed [K][WTR][CP]
__global__ __launch_bounds__(256) void k_wconv(
    const float* __restrict__ src, u16* __restrict__ dst,
    int K, int Cin, int Cout, int WTR, int CP) {
  long total = (long)K * WTR * CP;
  long stride = (long)gridDim.x * 256;
  for (long i = (long)blockIdx.x * 256 + threadIdx.x; i < total; i += stride) {
    int ci = (int)(i % CP);
    long t = i / CP;
    int co = (int)(t % WTR);
    int k = (int)(t / WTR);
    float v = 0.f;
    if (ci < Cin && co < Cout) v = src[((long)k * Cin + ci) * Cout + co];
    dst[i] = f2bf(v);
  }
}

// ---------------------------------------------------------------------------
extern "C" void kernel_launch(void* const* d_in, const int* in_sizes, int n_in,
                              void* d_out, int out_size, void* d_ws, size_t ws_size,
                              hipStream_t stream) {
  const float* features = (const float*)d_in[0];
  const int* nmap1 = (const int*)d_in[1];
  const int* cmap = (const int*)d_in[2];
  const int* nmap2 = (const int*)d_in[3];
  const int* b1 = (const int*)d_in[4];
  const int* b2 = (const int*)d_in[5];
  const int* b3 = (const int*)d_in[6];
  const float* W_d1 = (const float*)d_in[7];
  const float* W_d2 = (const float*)d_in[8];
  const float* Wd_d = (const float*)d_in[9];
  const float* W_f1 = (const float*)d_in[11];
  const float* W_f2 = (const float*)d_in[12];
  const float* Wd_f = (const float*)d_in[13];
  const float* W_i1 = (const float*)d_in[15];
  const float* W_i2 = (const float*)d_in[16];
  const float* Wd_i = (const float*)d_in[17];
  const float* W_e1a = (const float*)d_in[19];
  const float* W_e1b = (const float*)d_in[20];
  const float* W_ed = (const float*)d_in[21];
  const float* W_e2a = (const float*)d_in[23];
  const float* W_e2b = (const float*)d_in[24];
  const float* W_sub = (const float*)d_in[25];
  const float* b_sub = (const float*)d_in[26];
  const float* W_occ = (const float*)d_in[27];
  const float* b_occ = (const float*)d_in[28];
  const float* W_pi1 = (const float*)d_in[29];
  const float* W_pi2 = (const float*)d_in[30];
  const float* W_pi3 = (const float*)d_in[31];
  const float* b_pi3 = (const float*)d_in[32];
  const float* W_ps1 = (const float*)d_in[33];
  const float* W_ps2 = (const float*)d_in[34];
  const float* W_ps3 = (const float*)d_in[35];
  const float* b_ps3 = (const float*)d_in[36];
  const float* W_t = (const float*)d_in[37];

  const int N1 = in_sizes[4];
  const int N2 = in_sizes[5];

  // ---- workspace layout ----
  char* base = (char*)d_ws;
  size_t off = 0;
  auto alloc = [&](size_t bytes) -> void* {
    void* r = base + off;
    off += (bytes + 255) & ~(size_t)255;
    return r;
  };
  float* x = (float*)alloc((size_t)N1 * 192 * 4);        // fine features; aliased by cat_f32
  float* T = (float*)alloc((size_t)N1 * 256 * 4);        // trunk temps / t192
  float* Bq1 = T;
  float* Bq2 = T + (size_t)N1 * 64;
  float* Bq3 = T + (size_t)N1 * 128;
  float* Bq4 = T + (size_t)N1 * 192;
  float* t192 = T;
  u16* catb = (u16*)alloc((size_t)N2 * 192 * 2);
  u16* hb = (u16*)alloc((size_t)N2 * 192 * 2);
  u16* pib = (u16*)alloc((size_t)N2 * 192 * 2);
  u16* fullb = (u16*)alloc((size_t)N2 * 232 * 2);
  float* spf = (float*)alloc((size_t)N2 * 128 * 4);
  u16* WTpi1 = (u16*)alloc((size_t)27 * 192 * 192 * 2);
  u16* WTpi2 = (u16*)alloc((size_t)27 * 192 * 192 * 2);
  u16* WTps1 = (u16*)alloc((size_t)27 * 192 * 192 * 2);
  u16* WTps2 = (u16*)alloc((size_t)27 * 192 * 192 * 2);
  u16* WTpi3 = (u16*)alloc((size_t)27 * 32 * 192 * 2);
  u16* WTps3 = (u16*)alloc((size_t)27 * 32 * 192 * 2);
  u16* WTt = (u16*)alloc((size_t)8 * 64 * 256 * 2);
  float* stats = (float*)alloc((size_t)19 * 772 * 4);
  if (off > ws_size) return;  // workspace too small: bail (will fail loudly)

  float* catf = x;  // alias: x is dead once encoder residuals are built
  float* dout = (float*)d_out;
  float* out0 = dout;
  float* proxyp = dout + (size_t)N2 * 512;
  float* pip = proxyp + N2;
  float* psp = pip + (size_t)N2 * 17;

  hipMemsetAsync(stats, 0, (size_t)19 * 772 * 4, stream);

  // weight conversion for bf16 heads
  k_wconv<<<256, 256, 0, stream>>>(W_pi1, WTpi1, 27, 192, 192, 192, 192);
  k_wconv<<<256, 256, 0, stream>>>(W_pi2, WTpi2, 27, 192, 192, 192, 192);
  k_wconv<<<256, 256, 0, stream>>>(W_ps1, WTps1, 27, 192, 192, 192, 192);
  k_wconv<<<256, 256, 0, stream>>>(W_ps2, WTps2, 27, 192, 192, 192, 192);
  k_wconv<<<256, 256, 0, stream>>>(W_pi3, WTpi3, 27, 192, 17, 32, 192);
  k_wconv<<<256, 256, 0, stream>>>(W_ps3, WTps3, 27, 192, 20, 32, 192);
  k_wconv<<<256, 256, 0, stream>>>(W_t, WTt, 8, 229, 64, 64, 256);

  const int SG = 1024;   // stats grid
  const int AG = 1024;   // apply grid
  int slot = 0;
  struct Br { int aoff, Cin; const float *W1, *W2, *Wd; };
  Br brs[3] = {{0, 2, W_d1, W_d2, Wd_d},
               {2, 80, W_f1, W_f2, Wd_f},
               {82, 17, W_i1, W_i2, Wd_i}};

  // ---- fine branches (fp32 trunk) ----
  for (int b = 0; b < 3; ++b) {
    // dense residual: inorm(f @ Wd)  (bias is a no-op under inorm)
    k1_conv<<<dim3(cdiv(N1, 128), 1), 256, 0, stream>>>(
        features, 99, brs[b].aoff, brs[b].Cin, nullptr, 1, brs[b].Wd, 64, nullptr, Bq1, 64, N1, 0);
    k_stats<<<SG, 256, 0, stream>>>(Bq1, 64, N1, 64, b1, stats + slot * 772);
    k_apply<<<AG, 256, 0, stream>>>(Bq1, 64, N1, 64, b1, stats + slot * 772,
                                    nullptr, 0, 0, Bq3, 64, nullptr, 0);
    slot++;
    // conv1 + inorm + relu
    k1_conv<<<dim3(cdiv(N1, 128), 1), 256, 0, stream>>>(
        features, 99, brs[b].aoff, brs[b].Cin, nmap1, 27, brs[b].W1, 64, nullptr, Bq1, 64, N1, 0);
    k_stats<<<SG, 256, 0, stream>>>(Bq1, 64, N1, 64, b1, stats + slot * 772);
    k_apply<<<AG, 256, 0, stream>>>(Bq1, 64, N1, 64, b1, stats + slot * 772,
                                    nullptr, 0, 1, Bq2, 64, nullptr, 0);
    slot++;
    // conv2 + inorm + res + relu  -> x[:, b*64 : b*64+64]
    k1_conv<<<dim3(cdiv(N1, 128), 1), 256, 0, stream>>>(
        Bq2, 64, 0, 64, nmap1, 27, brs[b].W2, 64, nullptr, Bq4, 64, N1, 1);
    k_stats<<<SG, 256, 0, stream>>>(Bq4, 64, N1, 64, b1, stats + slot * 772);
    k_apply<<<AG, 256, 0, stream>>>(Bq4, 64, N1, 64, b1, stats + slot * 772,
                                    Bq3, 64, 1, x + b * 64, 192, nullptr, 0);
    slot++;
  }

  // ---- encoder (fp32 trunk) ----
  // e1a: downsample conv (cmap, K=8) + inorm + relu -> Bq2
  k1_conv<<<dim3(cdiv(N2, 128), 1), 256, 0, stream>>>(
      x, 192, 0, 192, cmap, 8, W_e1a, 64, nullptr, Bq1, 64, N2, 1);
  k_stats<<<SG, 256, 0, stream>>>(Bq1, 64, N2, 64, b2, stats + slot * 772);
  k_apply<<<AG, 256, 0, stream>>>(Bq1, 64, N2, 64, b2, stats + slot * 772,
                                  nullptr, 0, 1, Bq2, 64, nullptr, 0);
  slot++;
  // e1b conv -> Bq4 (norm applied later with res)
  k1_conv<<<dim3(cdiv(N2, 128), 1), 256, 0, stream>>>(
      Bq2, 64, 0, 64, nmap2, 27, W_e1b, 64, nullptr, Bq4, 64, N2, 1);
  k_stats<<<SG, 256, 0, stream>>>(Bq4, 64, N2, 64, b2, stats + slot * 772);
  int sl_e1b = slot; slot++;
  // ed: residual downsample conv + inorm (b_ed no-op) -> Bq3
  k1_conv<<<dim3(cdiv(N2, 128), 1), 256, 0, stream>>>(
      x, 192, 0, 192, cmap, 8, W_ed, 64, nullptr, Bq1, 64, N2, 1);
  k_stats<<<SG, 256, 0, stream>>>(Bq1, 64, N2, 64, b2, stats + slot * 772);
  k_apply<<<AG, 256, 0, stream>>>(Bq1, 64, N2, 64, b2, stats + slot * 772,
                                  nullptr, 0, 0, Bq3, 64, nullptr, 0);
  slot++;
  // enc_pre = relu(inorm(e1b) + res) -> Bq2
  k_apply<<<AG, 256, 0, stream>>>(Bq4, 64, N2, 64, b2, stats + sl_e1b * 772,
                                  Bq3, 64, 1, Bq2, 64, nullptr, 0);
  // _sbb(enc_pre): e2a conv + inorm + relu -> Bq3
  k1_conv<<<dim3(cdiv(N2, 128), 1), 256, 0, stream>>>(
      Bq2, 64, 0, 64, nmap2, 27, W_e2a, 64, nullptr, Bq1, 64, N2, 1);
  k_stats<<<SG, 256, 0, stream>>>(Bq1, 64, N2, 64, b2, stats + slot * 772);
  k_apply<<<AG, 256, 0, stream>>>(Bq1, 64, N2, 64, b2, stats + slot * 772,
                                  nullptr, 0, 1, Bq3, 64, nullptr, 0);
  slot++;
  // e2b conv + inorm + res(enc_pre) + relu -> enc (cat cols 0..63, f32+bf16)
  k1_conv<<<dim3(cdiv(N2, 128), 1), 256, 0, stream>>>(
      Bq3, 64, 0, 64, nmap2, 27, W_e2b, 64, nullptr, Bq4, 64, N2, 1);
  k_stats<<<SG, 256, 0, stream>>>(Bq4, 64, N2, 64, b2, stats + slot * 772);
  k_apply<<<AG, 256, 0, stream>>>(Bq4, 64, N2, 64, b2, stats + slot * 772,
                                  Bq2, 64, 1, catf, 192, catb, 192);
  slot++;

  // ---- sparse / proxy / mask (fp32) ----
  k1_conv<<<dim3(cdiv(N2, 128), 2), 256, 0, stream>>>(
      catf, 192, 0, 64, nullptr, 1, W_sub, 128, b_sub, spf, 128, N2, 1);
  k_mask<<<cdiv(N2, 4), 256, 0, stream>>>(spf, W_occ, b_occ, proxyp, catf, catb, N2);
  k_full<<<1024, 256, 0, stream>>>(catb, fullb, N2);

  // ---- heads (bf16 MFMA) ----
  const u16* WT1[2] = {WTpi1, WTps1};
  const u16* WT2[2] = {WTpi2, WTps2};
  const u16* WT3[2] = {WTpi3, WTps3};
  const float* b3v[2] = {b_pi3, b_ps3};
  float* outh[2] = {pip, psp};
  int co3[2] = {17, 20};
  int ld3[2] = {17, 20};
  int foff[2] = {192, 209};
  for (int h = 0; h < 2; ++h) {
    k2_conv<<<dim3(cdiv(N2, 128), 1), 256, 0, stream>>>(
        catb, 192, nmap2, 27, WT1[h], 192, 192, 192, nullptr, t192, 192, nullptr, 0, N2);
    k_stats<<<SG, 256, 0, stream>>>(t192, 192, N2, 192, b2, stats + slot * 772);
    k_apply<<<AG, 256, 0, stream>>>(t192, 192, N2, 192, b2, stats + slot * 772,
                                    nullptr, 0, 1, nullptr, 0, hb, 192);
    slot++;
    k2_conv<<<dim3(cdiv(N2, 128), 1), 256, 0, stream>>>(
        hb, 192, nmap2, 27, WT2[h], 192, 192, 192, nullptr, t192, 192, nullptr, 0, N2);
    k_stats<<<SG, 256, 0, stream>>>(t192, 192, N2, 192, b2, stats + slot * 772);
    k_apply<<<AG, 256, 0, stream>>>(t192, 192, N2, 192, b2, stats + slot * 772,
                                    catf, 192, 1, nullptr, 0, pib, 192);
    slot++;
    k2_conv<<<dim3(cdiv(N2, 128), 1), 256, 0, stream>>>(
        pib, 192, nmap2, 27, WT3[h], 32, 192, co3[h], b3v[h],
        outh[h], ld3[h], fullb + foff[h], 232, N2);
  }

  // ---- final einsum as ONE GEMM: out[m, k*64+co] = full[m] . W_t[k][:,co] ----
  // WTt layout [8][64][256] flattened == [512][256] with row r = k*64+co;
  // out row-major [M,512] matches out[(m*8+k)*64+co].
  k2_conv<<<dim3(cdiv(N2, 128), 3), 256, 0, stream>>>(
      fullb, 232, nullptr, 1, WTt, 512, 256, 512, nullptr,
      out0, 512, nullptr, 0, N2);

  // final inorm + relu over (N2*8, 64) rows with b3, in place in d_out
  k_stats<<<SG, 256, 0, stream>>>(out0, 64, N2 * 8, 64, b3, stats + slot * 772);
  k_apply<<<AG, 256, 0, stream>>>(out0, 64, N2 * 8, 64, b3, stats + slot * 772,
                                  nullptr, 0, 1, out0, 64, nullptr, 0);
}